// Round 1
// baseline (33.392 us; speedup 1.0000x reference)
//
#include <hip/hip_runtime.h>

#define B_N 2048
#define E_N 64
#define D_N 512
#define O_N 512
#define ON  64    // output columns per block
#define MC  32    // sample rows per chunk
#define XS_LD 520 // padded LDS row stride in bf16 elems (breaks bank conflicts)

typedef __bf16 bf16x8 __attribute__((ext_vector_type(8)));
typedef float  f32x4  __attribute__((ext_vector_type(4)));

__device__ __forceinline__ unsigned short f2bf(float f) {
  unsigned int u = __float_as_uint(f);
  u = (u + 0x7FFFu + ((u >> 16) & 1u)) >> 16;  // round-to-nearest-even
  return (unsigned short)u;
}

// Bucket samples by expert: cnt[e], list[e*B_N + slot] = b. Single block,
// LDS counters -> deterministic totals (order within a list is irrelevant:
// each sample's dot product is computed identically wherever it lands).
__global__ void bucket_kernel(const int* __restrict__ opt,
                              int* __restrict__ cnt,
                              int* __restrict__ list) {
  __shared__ int scnt[E_N];
  const int t = threadIdx.x;           // 1024 threads
  if (t < E_N) scnt[t] = 0;
  __syncthreads();
#pragma unroll
  for (int i = 0; i < B_N / 1024; ++i) {
    int b = t + i * 1024;
    int e = opt[b];
    int slot = atomicAdd(&scnt[e], 1);
    list[e * B_N + slot] = b;
  }
  __syncthreads();
  if (t < E_N) cnt[t] = scnt[t];
}

// Grouped GEMM: block = (expert e, 64-col o-tile). 256 threads = 4 waves,
// wave w owns cols [o0 + w*16, +16). Loop over 32-row sample chunks:
// stage x rows (fp32->bf16) into LDS once, stream weight from global with
// on-the-fly bf16 convert, 2 MFMAs (16x16x32) per wave per 32-k step.
__global__ __launch_bounds__(256)
void gemm_kernel(const float* __restrict__ x,
                 const float* __restrict__ w,
                 const float* __restrict__ bias,
                 const int* __restrict__ cnt,
                 const int* __restrict__ list,
                 float* __restrict__ out) {
  __shared__ unsigned short xs[MC * XS_LD];

  const int e    = blockIdx.x;
  const int o0   = blockIdx.y * ON;
  const int t    = threadIdx.x;
  const int lane = t & 63;
  const int wave = t >> 6;
  const int n    = cnt[e];
  const float* wexp = w + (size_t)e * D_N * O_N;
  const int m_in = lane & 15;   // A-row / B-col / D-col within 16
  const int g    = lane >> 4;   // k-group 0..3
  const int col  = o0 + wave * 16 + m_in;
  const float bval = bias[e * O_N + col];
  const int* mylist = list + e * B_N;

  for (int m0 = 0; m0 < n; m0 += MC) {
    __syncthreads();   // protect xs from readers of previous chunk
    // Stage MC rows x 512 cols: 4096 float4 loads over 256 threads.
#pragma unroll
    for (int i = 0; i < 16; ++i) {
      int idx = t + i * 256;
      int row = idx >> 7;       // /128 float4-per-row
      int c4  = idx & 127;
      int s   = m0 + row;
      unsigned short v0 = 0, v1 = 0, v2 = 0, v3 = 0;
      if (s < n) {
        int b = mylist[s];
        const float4 xv = *reinterpret_cast<const float4*>(x + (size_t)b * D_N + c4 * 4);
        v0 = f2bf(xv.x); v1 = f2bf(xv.y); v2 = f2bf(xv.z); v3 = f2bf(xv.w);
      }
      *reinterpret_cast<ushort4*>(&xs[row * XS_LD + c4 * 4]) = make_ushort4(v0, v1, v2, v3);
    }
    __syncthreads();

    f32x4 acc0 = {0.f, 0.f, 0.f, 0.f};
    f32x4 acc1 = {0.f, 0.f, 0.f, 0.f};

    for (int k0 = 0; k0 < D_N; k0 += 32) {
      const int kb = k0 + g * 8;
      // A fragments: one ds_read_b128 each (16B aligned: XS_LD*2 = 1040 = 65*16)
      union { uint4 u; bf16x8 v; } a0, a1;
      a0.u = *reinterpret_cast<const uint4*>(&xs[m_in * XS_LD + kb]);
      a1.u = *reinterpret_cast<const uint4*>(&xs[(m_in + 16) * XS_LD + kb]);
      // B fragment: 8 strided scalar loads (lanes 0..15 coalesce to 64B per k-row)
      union { unsigned short u[8]; bf16x8 v; } bf;
      const float* wp = wexp + (size_t)kb * O_N + col;
#pragma unroll
      for (int j = 0; j < 8; ++j) bf.u[j] = f2bf(wp[(size_t)j * O_N]);

      acc0 = __builtin_amdgcn_mfma_f32_16x16x32_bf16(a0.v, bf.v, acc0, 0, 0, 0);
      acc1 = __builtin_amdgcn_mfma_f32_16x16x32_bf16(a1.v, bf.v, acc1, 0, 0, 0);
    }

    // D layout (m89-verified): col = lane&15, row = (lane>>4)*4 + reg
#pragma unroll
    for (int r = 0; r < 4; ++r) {
      int sl = g * 4 + r;
      int s  = m0 + sl;
      if (s < n)      out[(size_t)mylist[s]  * O_N + col] = acc0[r] + bval;
      int s2 = m0 + 16 + sl;
      if (s2 < n)     out[(size_t)mylist[s2] * O_N + col] = acc1[r] + bval;
    }
  }
}

extern "C" void kernel_launch(void* const* d_in, const int* in_sizes, int n_in,
                              void* d_out, int out_size, void* d_ws, size_t ws_size,
                              hipStream_t stream) {
  const float* x      = (const float*)d_in[0];
  const int*   option = (const int*)d_in[1];
  const float* weight = (const float*)d_in[2];
  const float* bias   = (const float*)d_in[3];
  float* out = (float*)d_out;

  int* cnt  = (int*)d_ws;                       // 64 ints
  int* list = (int*)((char*)d_ws + 256);        // 64 * 2048 ints

  bucket_kernel<<<1, 1024, 0, stream>>>(option, cnt, list);
  gemm_kernel<<<dim3(E_N, O_N / ON), 256, 0, stream>>>(x, weight, bias, cnt, list, out);
}